// Round 1
// baseline (125.475 us; speedup 1.0000x reference)
//
#include <hip/hip_runtime.h>

// out[b,i,j] = s[b,i] * e[b,j] for 0 <= j - i <= 15, else 0.
// B=8, L=4096, fp32. Output 512 MiB -> pure write-BW-bound streaming kernel.

#define BAND 15
#define LDIM 4096

__global__ __launch_bounds__(256) void band_outer_kernel(
    const float* __restrict__ s,
    const float* __restrict__ e,
    float* __restrict__ out,
    int total4) {
  int idx = blockIdx.x * blockDim.x + threadIdx.x;
  int stride = gridDim.x * blockDim.x;
  float4* __restrict__ out4 = reinterpret_cast<float4*>(out);
  for (int t = idx; t < total4; t += stride) {
    // t indexes float4s: j4 = t % (L/4), row = t / (L/4); i = row % L, b = row / L
    int j4  = t & (LDIM / 4 - 1);
    int row = t >> 10;          // / (L/4)
    int i   = row & (LDIM - 1);
    int b   = row >> 12;        // / L
    int j0  = j4 << 2;

    float4 v = make_float4(0.f, 0.f, 0.f, 0.f);
    // band: i <= j <= i + BAND; this float4 covers j0..j0+3
    if (j0 + 3 >= i && j0 <= i + BAND) {
      float sv = s[b * LDIM + i];
      const float* eb = e + b * LDIM;
#pragma unroll
      for (int k = 0; k < 4; ++k) {
        int j = j0 + k;
        float val = (j >= i && j <= i + BAND) ? sv * eb[j] : 0.f;
        reinterpret_cast<float*>(&v)[k] = val;
      }
    }
    out4[t] = v;
  }
}

extern "C" void kernel_launch(void* const* d_in, const int* in_sizes, int n_in,
                              void* d_out, int out_size, void* d_ws, size_t ws_size,
                              hipStream_t stream) {
  const float* s = (const float*)d_in[0];
  const float* e = (const float*)d_in[1];
  float* out = (float*)d_out;

  int total4 = out_size / 4;  // number of float4 elements (8*4096*4096/4)
  int threads = 256;
  int blocks = 2048;  // 256 CU * 8 blocks/CU; grid-stride covers the rest
  band_outer_kernel<<<blocks, threads, 0, stream>>>(s, e, out, total4);
}

// Round 3
// 98.624 us; speedup vs baseline: 1.2723x; 1.2723x over previous
//
#include <hip/hip_runtime.h>

// out[b,i,j] = s[b,i] * e[b,j] for 0 <= j - i <= 15, else 0.
// B=8, L=4096, fp32 out (512 MiB) -> pure write-BW-bound.
//
// One wave (64 lanes) per output row: 16 float4 stores of 1 KiB each.
// Row index i is wave-uniform -> band-chunk test is a scalar branch,
// at most 2 of 16 chunks take the band path. Nontemporal stores skip
// L2 write-allocate (output is never re-read by us).
//
// Note: __builtin_nontemporal_store requires a native clang vector type,
// not HIP_vector_type<float,4>.

#define BAND 15
#define LDIM 4096
#define CHUNKS 16  // 4096 floats / (64 lanes * 4 floats/lane)

typedef float f32x4 __attribute__((ext_vector_type(4)));

__global__ __launch_bounds__(256) void band_outer_rows(
    const float* __restrict__ s,
    const float* __restrict__ e,
    float* __restrict__ out) {
  const int wave = threadIdx.x >> 6;
  const int lane = threadIdx.x & 63;
  const int row  = (blockIdx.x << 2) + wave;  // 0 .. B*L-1 (32768 rows)
  const int i    = row & (LDIM - 1);
  const int b    = row >> 12;

  const float sv = s[row];                    // wave-uniform broadcast load
  const float* __restrict__ eb = e + (b << 12);
  f32x4* __restrict__ out4 =
      reinterpret_cast<f32x4*>(out) + (size_t)row * (LDIM / 4) + lane;

  const int c_lo = i >> 8;            // first chunk touching the band
  const int c_hi = (i + BAND) >> 8;   // last chunk touching the band

  const f32x4 z = {0.f, 0.f, 0.f, 0.f};
#pragma unroll
  for (int c = 0; c < CHUNKS; ++c) {
    if (c == c_lo || c == c_hi) {     // wave-uniform scalar branch
      const int j0 = (c << 8) + (lane << 2);
      f32x4 v;
#pragma unroll
      for (int k = 0; k < 4; ++k) {
        const int j = j0 + k;
        v[k] = (j >= i && j - i <= BAND) ? sv * eb[j] : 0.f;
      }
      __builtin_nontemporal_store(v, out4 + c * 64);
    } else {
      __builtin_nontemporal_store(z, out4 + c * 64);
    }
  }
}

extern "C" void kernel_launch(void* const* d_in, const int* in_sizes, int n_in,
                              void* d_out, int out_size, void* d_ws, size_t ws_size,
                              hipStream_t stream) {
  const float* s = (const float*)d_in[0];
  const float* e = (const float*)d_in[1];
  float* out = (float*)d_out;

  // 8 * 4096 rows, 4 rows (waves) per 256-thread block
  const int rows = out_size / LDIM;   // 32768
  band_outer_rows<<<rows / 4, 256, 0, stream>>>(s, e, out);
}